// Round 3
// baseline (403.988 us; speedup 1.0000x reference)
//
#include <hip/hip_runtime.h>

// GraphFeaturesStackPad on MI355X.
// Stage 1: bf16 MFMA fused up/gate projection + sigmoid-gate + segment-sum
//          (atomicAdd into d_out used as graph_sums accumulator, fp32).
// Stage 2: fp32 in-place GEMM graph_sums @ W_func + b_func.
// d_ws usage: ntiles ints (~31 KB) for per-tile first-graph index.
//
// R5 changes vs R2/R4 (no counters yet -- static waitcnt/occupancy audit):
//  - ALL loop-body VMEM made unconditional via address clamping (per-lane
//    `if (n<V)` and `if (next<ntiles)` removed). Conditional VMEM forces the
//    waitcnt pass to merge paths conservatively -> vmcnt(0) drains of the
//    prefetch. Garbage rows beyond n_end-n0 are never read by the reduce,
//    so clamped duplicate loads need no zero-fill.
//  - s_starts LDS staging removed entirely: each wave loads the 64-entry
//    starts window into its lanes (starts[min(g0v+lane,G)]) and the reduce
//    broadcasts entries with __shfl. No ds_write, no bar placement hazard.
//  - window (g0v, sval) software-pipelined one tile ahead like ld[]:
//    issued after the prefetch, consumed next iteration's reduce -> retired
//    by then, and the tile_seg->starts dependent chain hides under compute.
//  - occupancy 2 -> 3 blocks/CU: LDS now 51 KB/block (x3 = 153 <= 160 KB),
//    __launch_bounds__(256,3), grid 512 -> 768. 12 waves/CU for latency
//    hiding (est. peak VGPR ~150 < 168 cap; VGPR_Count will confirm).

typedef __bf16 bf16_t;
typedef bf16_t bf16x8 __attribute__((ext_vector_type(8)));
typedef float  f32x4  __attribute__((ext_vector_type(4)));

#define XS_STRIDE 144   // shorts; 288 B row = 72 dwords -> 4-way banks on b128
#define GS_STRIDE 132   // floats; 2-way (free) on both write and read sides

__device__ __forceinline__ unsigned short f2bf(float f) {
  unsigned int u = __float_as_uint(f);
  u += 0x7fffu + ((u >> 16) & 1u);   // RNE
  return (unsigned short)(u >> 16);
}

// LDS-only barrier: drains LDS ops but leaves global loads (vmcnt) in flight,
// so the software-pipelined next-tile loads overlap the compute phases.
__device__ __forceinline__ void bar_lds() {
  asm volatile("s_waitcnt lgkmcnt(0)\n\ts_barrier" ::: "memory");
}

__global__ void tile_seg_kernel(const int* __restrict__ starts,
                                int* __restrict__ tile_seg,
                                int ntiles, int G) {
  int i = blockIdx.x * blockDim.x + threadIdx.x;
  if (i >= ntiles) return;
  int n0 = i * 64;
  int lo = 0, hi = G - 1;            // largest g with starts[g] <= n0
  while (lo < hi) {
    int mid = (lo + hi + 1) >> 1;
    if (starts[mid] <= n0) lo = mid; else hi = mid - 1;
  }
  tile_seg[i] = lo;
}

__global__ __launch_bounds__(256, 3)
void stage1_kernel(const float* __restrict__ X,
                   const float* __restrict__ Wu, const float* __restrict__ bu,
                   const float* __restrict__ Wg, const float* __restrict__ bg,
                   const int* __restrict__ starts,
                   const int* __restrict__ tile_seg,
                   float* __restrict__ gsum, int V, int G, int ntiles)
{
  __shared__ unsigned short Xs[64 * XS_STRIDE]; // bf16 tile (18.0 KB)
  __shared__ float          Gs[64 * GS_STRIDE]; // gated fp32 tile (33.0 KB)

  const int tid  = threadIdx.x;
  const int lane = tid & 63;
  const int wave = tid >> 6;          // 4 waves; wave owns f-strip [wave*32, +32)
  const int quad = lane >> 4;
  const int l15  = lane & 15;

  // Persistent B fragments (W_up / W_gate) in registers, loaded once per block.
  // B-frag layout: lane holds B[k = s*32 + quad*8 + j][n = lane&15].
  bf16x8 Bu[2][4], Bg[2][4];
  float bup[2], bgt[2];
#pragma unroll
  for (int t = 0; t < 2; ++t) {
    const int f = wave * 32 + t * 16 + l15;
    bup[t] = bu[f];
    bgt[t] = bg[f];
#pragma unroll
    for (int s = 0; s < 4; ++s) {
      const int k0 = s * 32 + quad * 8;
      union { unsigned short us[8]; bf16x8 v; } a, b;
#pragma unroll
      for (int j = 0; j < 8; ++j) {
        a.us[j] = f2bf(Wu[(k0 + j) * 128 + f]);
        b.us[j] = f2bf(Wg[(k0 + j) * 128 + f]);
      }
      Bu[t][s] = a.v;
      Bg[t][s] = b.v;
    }
  }

  f32x4 ld[8];
  int tile = blockIdx.x;

  // preload first tile's data + window (clamped, unconditional)
  int g0v, sval;
  {
    const int t0 = min(tile, ntiles - 1);
    g0v  = tile_seg[t0];
    sval = starts[min(g0v + lane, G)];
    const int n0 = t0 * 64;
#pragma unroll
    for (int i = 0; i < 8; ++i) {
      const int flat = tid + i * 256;
      const int n = min(n0 + (flat >> 5), V - 1);
      const int k = (flat & 31) << 2;
      ld[i] = *(const f32x4*)(X + (size_t)n * 128 + k);
    }
  }

  for (; tile < ntiles; tile += gridDim.x) {
    const int n0    = tile * 64;
    const int n_end = min(n0 + 64, V);
    const int g0 = g0v;     // this tile's window (pipelined in last iteration)
    const int sv = sval;

    // staged regs -> LDS as packed bf16 (8B ds_write); consumes the prefetch
#pragma unroll
    for (int i = 0; i < 8; ++i) {
      const int flat = tid + i * 256;
      const int n = flat >> 5;
      const int k = (flat & 31) << 2;
      const unsigned int p0 =
          (unsigned int)f2bf(ld[i][0]) | ((unsigned int)f2bf(ld[i][1]) << 16);
      const unsigned int p1 =
          (unsigned int)f2bf(ld[i][2]) | ((unsigned int)f2bf(ld[i][3]) << 16);
      *(uint2*)&Xs[n * XS_STRIDE + k] = make_uint2(p0, p1);
    }

    // issue next tile's global loads NOW (clamped, unconditional); they stay
    // in flight through the lgkm-only barriers and the MFMA/reduce phases
    const int nextc = min(tile + (int)gridDim.x, ntiles - 1);
    {
      const int m0 = nextc * 64;
#pragma unroll
      for (int i = 0; i < 8; ++i) {
        const int flat = tid + i * 256;
        const int n = min(m0 + (flat >> 5), V - 1);
        const int k = (flat & 31) << 2;
        ld[i] = *(const f32x4*)(X + (size_t)n * 128 + k);
      }
    }
    // pipeline next tile's starts window (consumed next iteration's reduce;
    // the tile_seg -> starts dependent chain hides under MFMA + reduce)
    g0v  = tile_seg[nextc];
    sval = starts[min(g0v + lane, G)];

    bar_lds();   // bar1: Xs writes visible; prefetch stays in flight

    // ---- MFMA phase: 4 node sub-tiles of 16; per wave 2 f-tiles x 2 mats ----
#pragma unroll
    for (int sub = 0; sub < 4; ++sub) {
      bf16x8 A[4];
      const int nl = sub * 16 + l15;   // A-frag: A[m=lane&15][k=quad*8+j]
#pragma unroll
      for (int s = 0; s < 4; ++s)
        A[s] = *(const bf16x8*)&Xs[nl * XS_STRIDE + s * 32 + quad * 8];
#pragma unroll
      for (int t = 0; t < 2; ++t) {
        f32x4 au = {0.f, 0.f, 0.f, 0.f};
        f32x4 ag = {0.f, 0.f, 0.f, 0.f};
#pragma unroll
        for (int s = 0; s < 4; ++s) {
          au = __builtin_amdgcn_mfma_f32_16x16x32_bf16(A[s], Bu[t][s], au, 0, 0, 0);
          ag = __builtin_amdgcn_mfma_f32_16x16x32_bf16(A[s], Bg[t][s], ag, 0, 0, 0);
        }
        // D layout: col=lane&15 (feature), row=quad*4+r (node)
        const int f = wave * 32 + t * 16 + l15;
#pragma unroll
        for (int r = 0; r < 4; ++r) {
          const float up = au[r] + bup[t];
          const float gt = ag[r] + bgt[t];
          const float gv = up * __builtin_amdgcn_rcpf(1.f + __expf(-gt));
          Gs[(sub * 16 + quad * 4 + r) * GS_STRIDE + f] = gv;
        }
      }
    }

    bar_lds();   // bar2: Gs visible to all waves

    // ---- segment reduction: per-graph row sums -> one atomic per (g,f) ----
    // starts window lives in this wave's lanes of sv; __shfl broadcasts.
    {
      const int fcol = tid & 127;
      const int half = tid >> 7;       // halves take alternating graphs
      int i = 0;
      int sg = __shfl(sv, 0);
      while (sg < n_end && i < 63) {
        const int snext = __shfl(sv, i + 1);
        if (((g0 + i) & 1) == half) {
          const int r0 = max(sg, n0) - n0;
          const int r1 = min(snext - 1, n_end) - n0;  // excludes graph's last node
          if (r1 > r0) {
            float a0 = 0.f, a1 = 0.f, a2 = 0.f, a3 = 0.f;
            int r = r0;
            for (; r + 4 <= r1; r += 4) {
              a0 += Gs[(r + 0) * GS_STRIDE + fcol];
              a1 += Gs[(r + 1) * GS_STRIDE + fcol];
              a2 += Gs[(r + 2) * GS_STRIDE + fcol];
              a3 += Gs[(r + 3) * GS_STRIDE + fcol];
            }
            for (; r < r1; ++r) a0 += Gs[r * GS_STRIDE + fcol];
            const float acc = (a0 + a1) + (a2 + a3);
            atomicAdd(&gsum[(size_t)(g0 + i) * 128 + fcol], acc);
          }
        }
        sg = snext;
        ++i;
      }
    }
    // no end-of-loop barrier: next iteration's bar1 fences Xs reuse (writes
    // happen only after all waves passed the previous bar2 + reduce reads of
    // Gs are fenced by next bar1 before new Gs writes)
  }
}

__global__ __launch_bounds__(256)
void stage2_kernel(const float* __restrict__ Wf, const float* __restrict__ bfv,
                   float* __restrict__ out, int G)
{
  __shared__ float Gsm[32 * 132];
  const int g0  = blockIdx.x * 32;
  const int tid = threadIdx.x;

  // stage this block's 32 graph_sums rows (then safe to overwrite in-place)
  for (int i = tid; i < 32 * 32; i += 256) {
    const int r = i >> 5;
    const int c = (i & 31) << 2;
    const int g = g0 + r;
    f32x4 v = {0.f, 0.f, 0.f, 0.f};
    if (g < G) v = *(const f32x4*)(out + (size_t)g * 128 + c);
    *(f32x4*)&Gsm[r * 132 + c] = v;
  }
  __syncthreads();

  const int fq  = tid & 31;
  const int f0  = fq << 2;            // 4 consecutive features
  const int grp = tid >> 5;           // 8 groups x 4 graphs
  float acc[4][4];
#pragma unroll
  for (int i = 0; i < 4; ++i)
#pragma unroll
    for (int j = 0; j < 4; ++j) acc[i][j] = 0.f;

#pragma unroll 4
  for (int k = 0; k < 128; ++k) {
    const f32x4 w = *(const f32x4*)(Wf + (size_t)k * 128 + f0);
#pragma unroll
    for (int i = 0; i < 4; ++i) {
      const float gv = Gsm[(grp * 4 + i) * 132 + k];
      acc[i][0] += gv * w[0];
      acc[i][1] += gv * w[1];
      acc[i][2] += gv * w[2];
      acc[i][3] += gv * w[3];
    }
  }

  const f32x4 bb = *(const f32x4*)(bfv + f0);
#pragma unroll
  for (int i = 0; i < 4; ++i) {
    const int g = g0 + grp * 4 + i;
    if (g < G) {
      f32x4 o = {acc[i][0] + bb[0], acc[i][1] + bb[1],
                 acc[i][2] + bb[2], acc[i][3] + bb[3]};
      *(f32x4*)(out + (size_t)g * 128 + f0) = o;
    }
  }
}

extern "C" void kernel_launch(void* const* d_in, const int* in_sizes, int n_in,
                              void* d_out, int out_size, void* d_ws, size_t ws_size,
                              hipStream_t stream)
{
  const float* X      = (const float*)d_in[0];
  const float* Wu     = (const float*)d_in[1];
  const float* bu     = (const float*)d_in[2];
  const float* Wg     = (const float*)d_in[3];
  const float* bg     = (const float*)d_in[4];
  const float* Wf     = (const float*)d_in[5];
  const float* bf_    = (const float*)d_in[6];
  const int*   starts = (const int*)d_in[7];

  const int G = in_sizes[7] - 1;
  const int V = in_sizes[0] / 128;
  const int ntiles = (V + 63) / 64;

  int*   tile_seg = (int*)d_ws;          // ntiles ints (~31 KB)
  float* gsum     = (float*)d_out;       // graph_sums accumulates in d_out

  hipMemsetAsync(d_out, 0, (size_t)G * 128 * sizeof(float), stream);
  tile_seg_kernel<<<(ntiles + 255) / 256, 256, 0, stream>>>(starts, tile_seg, ntiles, G);
  stage1_kernel<<<768, 256, 0, stream>>>(X, Wu, bu, Wg, bg, starts, tile_seg,
                                         gsum, V, G, ntiles);
  stage2_kernel<<<(G + 31) / 32, 256, 0, stream>>>(Wf, bf_, gsum, G);
}